// Round 3
// baseline (4964.176 us; speedup 1.0000x reference)
//
#include <hip/hip_runtime.h>

typedef unsigned short u16;
typedef unsigned int u32;
typedef __attribute__((ext_vector_type(8))) short short8;
typedef __attribute__((ext_vector_type(4))) float float4v;

#define B_SZ 4096
#define T_SZ 32
#define XD 256
#define HD 256
#define ZD 256
#define GD 128
#define YD 2

#define BM 32          // batch rows per block
#define NBLK (B_SZ / BM)   // 128 blocks

// bf16 weight fragment buffer layout in d_ws (elem offsets) — frag-contiguous:
// addr = base + ((ntile*KT + kt)<<9) + lane*8 + j ; lane=(n&15)|(((k>>3)&3)<<4), j=k&7
#define W1_OFF 0              // [Wr|Wu]  N=512 (32 ntiles), KT=24
#define W2_OFF 393216         // Wh       N=256 (16 ntiles), KT=24
#define W3_OFF 589824         // [Wzp|Wzq] N=512 (32 ntiles), KT=17 (K=544: x,h,y+pad)
#define W4_OFF 868352         // [Wpm|Wps|Wqm|Wqs] N=1024 (64 ntiles), KT=8
#define WG_OFF 1130496        // Wg       N=128 (8 ntiles),  KT=24
#define WTOT   1228800

#define YTOT  (B_SZ*T_SZ*YD)        // 262144
#define KLTOT (B_SZ*T_SZ)           // 131072

__device__ __forceinline__ u16 f2bf(float f) {
    u32 u = __float_as_uint(f);
    u32 r = (u + 0x7fffu + ((u >> 16) & 1u)) >> 16;
    return (u16)r;
}
__device__ __forceinline__ float tanh_f(float x) {
    float e = __expf(2.f * x);
    return 1.f - 2.f / (e + 1.f);
}
__device__ __forceinline__ float sigm_f(float x) {
    return 1.f / (1.f + __expf(-x));
}

// a_ga: 48 tiles (mt*24+kt) of 512 elems, frag-contiguous
__device__ __forceinline__ int aga_off(int r, int k) {
    return (((r >> 4) * 24 + (k >> 5)) << 9) + ((((k >> 3) & 3) * 16 + (r & 15)) << 3) + (k & 7);
}
// a3s: 32 tiles ((pq*2+mt)*8+kt) of 512 elems
__device__ __forceinline__ int a3s_off(int r, int k, int pq) {
    return (((pq * 2 + (r >> 4)) * 8 + (k >> 5)) << 9) + ((((k >> 3) & 3) * 16 + (r & 15)) << 3) + (k & 7);
}

#define MFMA(a, b, c) __builtin_amdgcn_mfma_f32_16x16x32_bf16(a, b, c, 0, 0, 0)

// ---------------------------------------------------------------------------
__global__ void prep_weights(const float* __restrict__ Wr, const float* __restrict__ Wu,
                             const float* __restrict__ Wh, const float* __restrict__ Wzp,
                             const float* __restrict__ Wzq, const float* __restrict__ Wpm,
                             const float* __restrict__ Wps, const float* __restrict__ Wqm,
                             const float* __restrict__ Wqs, const float* __restrict__ Wg,
                             u16* __restrict__ wts, u32* __restrict__ bar)
{
    int o = blockIdx.x * 256 + threadIdx.x;
    if (o == 0) *bar = 0;          // reset soft-barrier counter every launch
    if (o >= WTOT) return;
    int mat, w, KT;
    if (o < W2_OFF)      { mat = 0; w = o;          KT = 24; }
    else if (o < W3_OFF) { mat = 1; w = o - W2_OFF; KT = 24; }
    else if (o < W4_OFF) { mat = 2; w = o - W3_OFF; KT = 17; }
    else if (o < WG_OFF) { mat = 3; w = o - W4_OFF; KT = 8;  }
    else                 { mat = 4; w = o - WG_OFF; KT = 24; }
    int nt  = w / (KT * 512);
    int rem = w - nt * (KT * 512);
    int kt  = rem >> 9;
    int q   = rem & 511;
    int lane = q >> 3, j = q & 7;
    int n = (nt << 4) | (lane & 15);
    int k = (kt << 5) + ((lane >> 4) << 3) + j;
    float v = 0.f;
    switch (mat) {
        case 0: v = (n < 256) ? Wr[k * 256 + n] : Wu[k * 256 + (n - 256)]; break;
        case 1: v = Wh[k * 256 + n]; break;
        case 2: v = (n < 256) ? (k < 512 ? Wzp[k * 256 + n] : 0.f)
                              : (k < 514 ? Wzq[k * 256 + (n - 256)] : 0.f); break;
        case 3: { int sel = n >> 8; int nn = n & 255;
                  const float* s = (sel == 0) ? Wpm : (sel == 1) ? Wps : (sel == 2) ? Wqm : Wqs;
                  v = s[k * 256 + nn]; } break;
        default: v = Wg[k * 128 + n]; break;
    }
    wts[o] = f2bf(v);
}

// ---------------------------------------------------------------------------
__global__ __launch_bounds__(1024, 4) void vrnn_all(
    const float* __restrict__ x,   const float* __restrict__ y_ph,
    const int*   __restrict__ Tph, const float* __restrict__ h0,
    const float* __restrict__ z0,  const float* __restrict__ eps,
    const float* __restrict__ br,  const float* __restrict__ bu,
    const float* __restrict__ bh,  const float* __restrict__ bzp,
    const float* __restrict__ bpm, const float* __restrict__ bps,
    const float* __restrict__ bzq, const float* __restrict__ bqm,
    const float* __restrict__ bqs, const float* __restrict__ bg,
    const float* __restrict__ by,  const float* __restrict__ Wy,
    const u16*   __restrict__ wts, u32* __restrict__ bar,
    float* __restrict__ out)
{
    __shared__ __align__(16) u16   a_ga[48 * 512];   // 49.2 KB  [x|h|z] frag tiles
    __shared__ __align__(16) u16   a3s[32 * 512];    // 32.8 KB  [hzp|hzq] frag tiles
    __shared__ float part[8 * BM * 2];               // 2 KB  y-head partials
    __shared__ float kl_acc[BM];
    __shared__ int   tph_s[BM];

    const int tid  = threadIdx.x;
    const int wv   = tid >> 6;
    const int lane = tid & 63;
    const int quad = lane >> 4;
    const int l15  = lane & 15;
    const int b0   = blockIdx.x * BM;
    const int cst  = wv * 16 + l15;     // this wave's column slice (all 256-col stages)

    // --- per-lane register-resident biases / Wy ---
    const float br_r  = br[cst],  bu_r = bu[cst], bh_r = bh[cst];
    const float bzp_r = bzp[cst], bzq_r = bzq[cst];
    const float b4pm = bpm[cst], b4ps = bps[cst], b4qm = bqm[cst], b4qs = bqs[cst];
    const int c5  = (wv >> 1) * 16 + l15;   // stage5 col
    const int mt5 = wv & 1;
    const float bg_r = bg[c5];
    const float wy0 = Wy[c5 * 2], wy1 = Wy[c5 * 2 + 1];
    const float by0 = by[0], by1 = by[1];

    if (tid < BM) tph_s[tid] = Tph[b0 + tid];

    // --- init h (registers at (row=mt*16+quad*4+i, col=cst)) + a_ga h/z bf16 ---
    float h_reg[2][4];
    float u_reg[2][4];
#pragma unroll
    for (int mt = 0; mt < 2; ++mt)
#pragma unroll
        for (int i = 0; i < 4; ++i)
            h_reg[mt][i] = h0[(size_t)(b0 + mt * 16 + quad * 4 + i) * HD + cst];
    {
        int r = tid >> 5, cc = (tid & 31) * 8;
        const float* hp = &h0[(b0 + r) * HD + cc];
        const float* zp = &z0[(b0 + r) * ZD + cc];
        short8 hv, zv;
#pragma unroll
        for (int j = 0; j < 8; ++j) {
            hv[j] = (short)f2bf(hp[j]);
            zv[j] = (short)f2bf(zp[j]);
        }
        *(short8*)&a_ga[aga_off(r, 256 + cc)] = hv;
        *(short8*)&a_ga[aga_off(r, 512 + cc)] = zv;
    }
    __syncthreads();

    const float4v zero4 = {0.f, 0.f, 0.f, 0.f};

    for (int t = 0; t < T_SZ; ++t) {
        // --- stage x_t into a_ga cols [0,256) ---
        {
            int r = tid >> 5, cc = (tid & 31) * 8;
            const float* xp = &x[((size_t)(b0 + r) * T_SZ + t) * XD + cc];
            short8 xv;
#pragma unroll
            for (int j = 0; j < 8; ++j) xv[j] = (short)f2bf(xp[j]);
            *(short8*)&a_ga[aga_off(r, cc)] = xv;
        }
        __syncthreads();   // bar1

        // ============ stage 1: r,u = sigmoid([x,h,z] @ W1), cols cst ============
        {
            const u16* pB0 = wts + W1_OFF + ((wv * 24) << 9) + lane * 8;          // ntile wv   (r)
            const u16* pB1 = wts + W1_OFF + (((16 + wv) * 24) << 9) + lane * 8;   // ntile 16+wv (u)
            short8 b0p[3], b1p[3];
#pragma unroll
            for (int d = 0; d < 3; ++d) {
                b0p[d] = *(const short8*)(pB0 + (d << 9));
                b1p[d] = *(const short8*)(pB1 + (d << 9));
            }
            float4v aR0 = zero4, aR1 = zero4, aU0 = zero4, aU1 = zero4;
#pragma unroll
            for (int kt = 0; kt < 24; ++kt) {
                short8 b0c = b0p[kt % 3];
                short8 b1c = b1p[kt % 3];
                if (kt + 3 < 24) {
                    b0p[kt % 3] = *(const short8*)(pB0 + ((kt + 3) << 9));
                    b1p[kt % 3] = *(const short8*)(pB1 + ((kt + 3) << 9));
                }
                short8 aF0 = *(const short8*)&a_ga[(kt << 9) + lane * 8];
                short8 aF1 = *(const short8*)&a_ga[((24 + kt) << 9) + lane * 8];
                aR0 = MFMA(aF0, b0c, aR0); aR1 = MFMA(aF1, b0c, aR1);
                aU0 = MFMA(aF0, b1c, aU0); aU1 = MFMA(aF1, b1c, aU1);
            }
            __syncthreads();   // bar2: a_ga reads done before rh overwrite
#pragma unroll
            for (int mt = 0; mt < 2; ++mt) {
                float4v vR = (mt == 0) ? aR0 : aR1;
                float4v vU = (mt == 0) ? aU0 : aU1;
#pragma unroll
                for (int i = 0; i < 4; ++i) {
                    int row = mt * 16 + quad * 4 + i;
                    float rr = sigm_f(vR[i] + br_r);
                    u_reg[mt][i] = sigm_f(vU[i] + bu_r);
                    a_ga[aga_off(row, 256 + cst)] = f2bf(rr * h_reg[mt][i]);
                }
            }
            __syncthreads();   // bar3
        }

        // ============ stage 2: h_tilde = tanh([x,rh,z] @ Wh); h update ============
        {
            const u16* pB = wts + W2_OFF + ((wv * 24) << 9) + lane * 8;
            short8 bp[3];
#pragma unroll
            for (int d = 0; d < 3; ++d) bp[d] = *(const short8*)(pB + (d << 9));
            float4v a0 = zero4, a1 = zero4;
#pragma unroll
            for (int kt = 0; kt < 24; ++kt) {
                short8 bc = bp[kt % 3];
                if (kt + 3 < 24) bp[kt % 3] = *(const short8*)(pB + ((kt + 3) << 9));
                short8 aF0 = *(const short8*)&a_ga[(kt << 9) + lane * 8];
                short8 aF1 = *(const short8*)&a_ga[((24 + kt) << 9) + lane * 8];
                a0 = MFMA(aF0, bc, a0);
                a1 = MFMA(aF1, bc, a1);
            }
            __syncthreads();   // bar4: a_ga reads done before h / y writes
#pragma unroll
            for (int mt = 0; mt < 2; ++mt) {
                float4v va = (mt == 0) ? a0 : a1;
#pragma unroll
                for (int i = 0; i < 4; ++i) {
                    int row = mt * 16 + quad * 4 + i;
                    float ht = tanh_f(va[i] + bh_r);
                    float uu = u_reg[mt][i];
                    float h  = (1.f - uu) * h_reg[mt][i] + uu * ht;
                    h_reg[mt][i] = h;
                    a_ga[aga_off(row, 256 + cst)] = f2bf(h);
                }
            }
            // y_t + zeros into cols [512,544) (tile kt=16)
            if (tid < 128) {
                int r = tid >> 2, grp = tid & 3;
                short8 v = {0, 0, 0, 0, 0, 0, 0, 0};
                if (grp == 0) {
                    const float* yp = &y_ph[((size_t)(b0 + r) * T_SZ + t) * YD];
                    v[0] = (short)f2bf(yp[0]);
                    v[1] = (short)f2bf(yp[1]);
                }
                *(short8*)&a_ga[aga_off(r, 512 + grp * 8)] = v;
            }
            __syncthreads();   // bar5
        }

        // ============ stage 3: hzp,hzq = tanh([x,h,y] @ W3), cols cst ============
        {
            const u16* pB0 = wts + W3_OFF + ((wv * 17) << 9) + lane * 8;          // ntile wv (zp)
            const u16* pB1 = wts + W3_OFF + (((16 + wv) * 17) << 9) + lane * 8;   // ntile 16+wv (zq)
            short8 b0p[3], b1p[3];
#pragma unroll
            for (int d = 0; d < 3; ++d) {
                b0p[d] = *(const short8*)(pB0 + (d << 9));
                b1p[d] = *(const short8*)(pB1 + (d << 9));
            }
            float4v aP0 = zero4, aP1 = zero4, aQ0 = zero4, aQ1 = zero4;
#pragma unroll
            for (int kt = 0; kt < 17; ++kt) {
                short8 b0c = b0p[kt % 3];
                short8 b1c = b1p[kt % 3];
                if (kt + 3 < 17) {
                    b0p[kt % 3] = *(const short8*)(pB0 + ((kt + 3) << 9));
                    b1p[kt % 3] = *(const short8*)(pB1 + ((kt + 3) << 9));
                }
                short8 aF0 = *(const short8*)&a_ga[(kt << 9) + lane * 8];
                short8 aF1 = *(const short8*)&a_ga[((24 + kt) << 9) + lane * 8];
                aP0 = MFMA(aF0, b0c, aP0); aP1 = MFMA(aF1, b0c, aP1);
                aQ0 = MFMA(aF0, b1c, aQ0); aQ1 = MFMA(aF1, b1c, aQ1);
            }
            // a3s write needs no pre-barrier (last read one step ago)
#pragma unroll
            for (int mt = 0; mt < 2; ++mt) {
                float4v vP = (mt == 0) ? aP0 : aP1;
                float4v vQ = (mt == 0) ? aQ0 : aQ1;
#pragma unroll
                for (int i = 0; i < 4; ++i) {
                    int row = mt * 16 + quad * 4 + i;
                    a3s[a3s_off(row, cst, 0)] = f2bf(tanh_f(vP[i] + bzp_r));
                    a3s[a3s_off(row, cst, 1)] = f2bf(tanh_f(vQ[i] + bzq_r));
                }
            }
            if (tid < BM) kl_acc[tid] = 0.f;
            __syncthreads();   // bar6
        }

        // ============ stage 4: mu/s heads, z_post, KL (z-col = cst) ============
        {
            // eps early-issue (overlaps GEMM)
            float eps_r[2][4];
#pragma unroll
            for (int mt = 0; mt < 2; ++mt)
#pragma unroll
                for (int i = 0; i < 4; ++i) {
                    int row = mt * 16 + quad * 4 + i;
                    eps_r[mt][i] = eps[((size_t)t * B_SZ + (b0 + row)) * ZD + cst];
                }
            const u16* pW = wts + W4_OFF + ((wv * 8) << 9) + lane * 8;
            const int selstr = (128 << 9);   // 16 ntiles * 8 kt * 512
            float4v ac[4][2];
#pragma unroll
            for (int m = 0; m < 4; ++m) { ac[m][0] = zero4; ac[m][1] = zero4; }
            short8 cur[4];
#pragma unroll
            for (int s = 0; s < 4; ++s) cur[s] = *(const short8*)(pW + s * selstr);
#pragma unroll
            for (int kt = 0; kt < 8; ++kt) {
                short8 nxt[4];
                if (kt + 1 < 8) {
#pragma unroll
                    for (int s = 0; s < 4; ++s)
                        nxt[s] = *(const short8*)(pW + s * selstr + ((kt + 1) << 9));
                }
                short8 aP0 = *(const short8*)&a3s[((0 + kt) << 9) + lane * 8];
                short8 aP1 = *(const short8*)&a3s[((8 + kt) << 9) + lane * 8];
                short8 aQ0 = *(const short8*)&a3s[((16 + kt) << 9) + lane * 8];
                short8 aQ1 = *(const short8*)&a3s[((24 + kt) << 9) + lane * 8];
                ac[0][0] = MFMA(aP0, cur[0], ac[0][0]); ac[0][1] = MFMA(aP1, cur[0], ac[0][1]);
                ac[1][0] = MFMA(aP0, cur[1], ac[1][0]); ac[1][1] = MFMA(aP1, cur[1], ac[1][1]);
                ac[2][0] = MFMA(aQ0, cur[2], ac[2][0]); ac[2][1] = MFMA(aQ1, cur[2], ac[2][1]);
                ac[3][0] = MFMA(aQ0, cur[3], ac[3][0]); ac[3][1] = MFMA(aQ1, cur[3], ac[3][1]);
                if (kt + 1 < 8) {
#pragma unroll
                    for (int s = 0; s < 4; ++s) cur[s] = nxt[s];
                }
            }
            float kls[2][4];
#pragma unroll
            for (int mt = 0; mt < 2; ++mt)
#pragma unroll
                for (int i = 0; i < 4; ++i) {
                    int row = mt * 16 + quad * 4 + i;
                    float mu_p = ac[0][mt][i] + b4pm;
                    float s_p  = ac[1][mt][i] + b4ps;
                    float mu_q = ac[2][mt][i] + b4qm;
                    float s_q  = ac[3][mt][i] + b4qs;
                    float zpost = mu_q + __expf(0.5f * s_q) * eps_r[mt][i];
                    float dmu = mu_q - mu_p;
                    kls[mt][i] = 0.5f * (s_p - s_q)
                               + (__expf(s_q) + dmu * dmu) * 0.5f * __expf(-s_p) - 0.5f;
                    a_ga[aga_off(row, 512 + cst)] = f2bf(zpost);
                }
#pragma unroll
            for (int mt = 0; mt < 2; ++mt)
#pragma unroll
                for (int i = 0; i < 4; ++i) {
                    float v = kls[mt][i];
                    v += __shfl_xor(v, 1); v += __shfl_xor(v, 2);
                    v += __shfl_xor(v, 4); v += __shfl_xor(v, 8);
                    if (l15 == 0) atomicAdd(&kl_acc[mt * 16 + quad * 4 + i], v);
                }
            __syncthreads();   // bar7
            if (tid < BM)
                out[YTOT + (size_t)(b0 + tid) * T_SZ + t] = kl_acc[tid];
        }

        // ============ stage 5: g = tanh([x,h,z] @ Wg); y, g_T ============
        {
            const u16* pB = wts + WG_OFF + (((wv >> 1) * 24) << 9) + lane * 8;
            short8 bp[3];
#pragma unroll
            for (int d = 0; d < 3; ++d) bp[d] = *(const short8*)(pB + (d << 9));
            float4v a5 = zero4;
            const int abase = mt5 * 24;
#pragma unroll
            for (int kt = 0; kt < 24; ++kt) {
                short8 bc = bp[kt % 3];
                if (kt + 3 < 24) bp[kt % 3] = *(const short8*)(pB + ((kt + 3) << 9));
                short8 aF = *(const short8*)&a_ga[((abase + kt) << 9) + lane * 8];
                a5 = MFMA(aF, bc, a5);
            }
            float g[4];
#pragma unroll
            for (int i = 0; i < 4; ++i) {
                int row = mt5 * 16 + quad * 4 + i;
                g[i] = tanh_f(a5[i] + bg_r);
                if (tph_s[row] - 1 == t)
                    out[YTOT + KLTOT + (size_t)(b0 + row) * GD + c5] = g[i];
            }
#pragma unroll
            for (int i = 0; i < 4; ++i) {
                float p0 = g[i] * wy0, p1 = g[i] * wy1;
                p0 += __shfl_xor(p0, 1); p0 += __shfl_xor(p0, 2);
                p0 += __shfl_xor(p0, 4); p0 += __shfl_xor(p0, 8);
                p1 += __shfl_xor(p1, 1); p1 += __shfl_xor(p1, 2);
                p1 += __shfl_xor(p1, 4); p1 += __shfl_xor(p1, 8);
                if (l15 == 0) {
                    int row = mt5 * 16 + quad * 4 + i;
                    part[((wv >> 1) * BM + row) * 2]     = p0;
                    part[((wv >> 1) * BM + row) * 2 + 1] = p1;
                }
            }
            __syncthreads();   // bar8
            if (tid < BM) {
                int r = tid;
                float s0 = by0, s1 = by1;
#pragma unroll
                for (int j = 0; j < 8; ++j) {
                    s0 += part[(j * BM + r) * 2];
                    s1 += part[(j * BM + r) * 2 + 1];
                }
                float mx = fmaxf(s0, s1);
                float e0 = __expf(s0 - mx), e1 = __expf(s1 - mx);
                float inv = 1.f / (e0 + e1);
                size_t yoff = ((size_t)(b0 + r) * T_SZ + t) * YD;
                out[yoff]     = e0 * inv;
                out[yoff + 1] = e1 * inv;
            }
        }

        // ============ soft per-step grid barrier (perf pacing only) ============
        if (t + 1 < T_SZ) {
            __syncthreads();
            if (tid == 0) {
                __hip_atomic_fetch_add(bar, 1u, __ATOMIC_RELAXED, __HIP_MEMORY_SCOPE_AGENT);
                u32 target = (u32)NBLK * (u32)(t + 1);
                int guard = 0;
                while (__hip_atomic_load(bar, __ATOMIC_RELAXED, __HIP_MEMORY_SCOPE_AGENT) < target
                       && guard < (1 << 22)) {
                    __builtin_amdgcn_s_sleep(2);
                    ++guard;
                }
            }
            __syncthreads();
        }
    }
}

extern "C" void kernel_launch(void* const* d_in, const int* in_sizes, int n_in,
                              void* d_out, int out_size, void* d_ws, size_t ws_size,
                              hipStream_t stream)
{
    const float* x   = (const float*)d_in[0];
    const float* yph = (const float*)d_in[1];
    const int*   Tph = (const int*)  d_in[2];
    const float* h0  = (const float*)d_in[3];
    const float* z0  = (const float*)d_in[4];
    const float* eps = (const float*)d_in[5];
    const float* Wr  = (const float*)d_in[6];
    const float* br  = (const float*)d_in[7];
    const float* Wu  = (const float*)d_in[8];
    const float* bu  = (const float*)d_in[9];
    const float* Wh  = (const float*)d_in[10];
    const float* bh  = (const float*)d_in[11];
    const float* Wzp = (const float*)d_in[12];
    const float* bzp = (const float*)d_in[13];
    const float* Wpm = (const float*)d_in[14];
    const float* bpm = (const float*)d_in[15];
    const float* Wps = (const float*)d_in[16];
    const float* bps = (const float*)d_in[17];
    const float* Wzq = (const float*)d_in[18];
    const float* bzq = (const float*)d_in[19];
    const float* Wqm = (const float*)d_in[20];
    const float* bqm = (const float*)d_in[21];
    const float* Wqs = (const float*)d_in[22];
    const float* bqs = (const float*)d_in[23];
    const float* Wg  = (const float*)d_in[24];
    const float* bg  = (const float*)d_in[25];
    const float* Wy  = (const float*)d_in[26];
    const float* by  = (const float*)d_in[27];
    u16* wts = (u16*)d_ws;
    u32* bar = (u32*)((char*)d_ws + (size_t)WTOT * 2);
    float* out = (float*)d_out;

    hipLaunchKernelGGL(prep_weights, dim3((WTOT + 255) / 256), dim3(256), 0, stream,
                       Wr, Wu, Wh, Wzp, Wzq, Wpm, Wps, Wqm, Wqs, Wg, wts, bar);
    hipLaunchKernelGGL(vrnn_all, dim3(NBLK), dim3(1024), 0, stream,
                       x, yph, Tph, h0, z0, eps, br, bu, bh, bzp, bpm, bps,
                       bzq, bqm, bqs, bg, by, Wy, wts, bar, out);
}